// Round 2
// baseline (780.475 us; speedup 1.0000x reference)
//
#include <hip/hip_runtime.h>

// SequentialChart: ops < START(256) => steps independent. Algebraic cut:
// PL[b,op]=U_left@h(b,op), PR[b,op]=U_right@h(b,op) (16x fewer FLOPs),
// preact = PL[opL]+PR[opR] (bias folded into PL at GEMM epilogue).
// log2e folded into U/bias at cvt time: gates use raw v_exp_f32 (exp2).
// GEMM: 256x256 8-phase schedule (T2 swizzle + T3/T4 counted vmcnt + T5
// setprio), BK=64, 8 waves, 128KB LDS double-buffer, merged over all bg
// (1280 blocks = exactly 5 rounds at 1 block/CU). Runtime ws_size check
// falls back to per-bg dispatches.
// Fused gates+softmax+combine: c in 64KB LDS, h in packed-bf16 regs,
// cross-wave h-reduction through reused LDS -> 2 blocks/CU.

typedef unsigned int u32;
typedef unsigned short u16;
typedef __attribute__((ext_vector_type(8))) short short8;
typedef __attribute__((ext_vector_type(4))) float f32x4;
typedef __attribute__((ext_vector_type(4))) u16 u16x4;
typedef __attribute__((ext_vector_type(8))) u16 u16x8;
typedef _Float16 h8 __attribute__((ext_vector_type(8)));

#define CHART_ROWS 384
#define L2E 1.4426950408889634f

__device__ __forceinline__ u16 f2bf(float f) {           // fp32 -> bf16 RNE
  u32 u = __float_as_uint(f);
  u32 r = u + 0x7fffu + ((u >> 16) & 1u);
  return (u16)(r >> 16);
}
__device__ __forceinline__ float bf2f(u16 v) { return __uint_as_float(((u32)v) << 16); }
// preact pre-scaled by -log2e: sigmoid(x) = 1/(1+2^(-x*log2e))
__device__ __forceinline__ float sig2(float p) {
  return __builtin_amdgcn_rcpf(1.0f + __builtin_amdgcn_exp2f(p));
}
// preact pre-scaled by +2*log2e: tanh(x) = 1 - 2/(1+2^(2x*log2e))
__device__ __forceinline__ float tanh2(float p) {
  return 1.0f - 2.0f * __builtin_amdgcn_rcpf(1.0f + __builtin_amdgcn_exp2f(p));
}
// runtime-argument tanh (for tanh(c)); compiler folds 2*log2e into one mul
__device__ __forceinline__ float fast_tanh(float x) {
  return 1.0f - 2.0f * __builtin_amdgcn_rcpf(1.0f + __builtin_amdgcn_exp2f(2.0f * L2E * x));
}

__device__ __forceinline__ void async16(const void* g, void* l) {
  __builtin_amdgcn_global_load_lds((const __attribute__((address_space(1))) u32*)g,
                                   (__attribute__((address_space(3))) u32*)l, 16, 0, 0);
}

#define BAR() __builtin_amdgcn_s_barrier()
#define VMCNT4 asm volatile("s_waitcnt vmcnt(4)" ::: "memory")
#define VMCNT0 asm volatile("s_waitcnt vmcnt(0)" ::: "memory")

// ---- U (5120x2048 fp32) -> bf16, scaled by -log2e (sigmoid rows) / +2log2e (u rows)
__global__ void k_cvt_u(const float4* __restrict__ U4, u16* __restrict__ Ubf) {
  int i = blockIdx.x * blockDim.x + threadIdx.x;   // 2,621,440 threads
  int row = i >> 9;                                // 512 float4 per 2048-col row
  float sc = (row < 4096) ? -L2E : (2.0f * L2E);
  float4 v = U4[i];
  u16x4 o = {f2bf(v.x * sc), f2bf(v.y * sc), f2bf(v.z * sc), f2bf(v.w * sc)};
  *(u16x4*)(Ubf + (size_t)i * 4) = o;
}

// ---- chart rows<256: h-half -> chb, c-half -> chc; also copy rows<256 to out
__global__ void k_cvt_chart(const float* __restrict__ chart,
                            u16* __restrict__ chb, u16* __restrict__ chc,
                            float* __restrict__ out) {
  int i = blockIdx.x * blockDim.x + threadIdx.x;   // 2,097,152 threads
  int row = i >> 8;                 // b*256 + op, < 8192
  int k4 = (i & 255) * 4;
  int b = row >> 8, op = row & 255;
  const size_t base = (size_t)(b * CHART_ROWS + op) * 2048;
  const float4 vh = *(const float4*)(chart + base + 1024 + k4);
  const float4 vc = *(const float4*)(chart + base + k4);
  u16x4 oh = {f2bf(vh.x), f2bf(vh.y), f2bf(vh.z), f2bf(vh.w)};
  u16x4 oc = {f2bf(vc.x), f2bf(vc.y), f2bf(vc.z), f2bf(vc.w)};
  *(u16x4*)(chb + (size_t)row * 1024 + k4) = oh;
  *(u16x4*)(chc + (size_t)row * 1024 + k4) = oc;
  *(float4*)(out + base + k4) = vc;          // rows < 256 pass through
  *(float4*)(out + base + 1024 + k4) = vh;   // rows >= 256 written by k_fused
}

// ---- P[bgh][2048 rows][5120] = chb-rows @ U-half (+bias*scale on half0)
// 256x256 tile, BK=64, 8 waves (2Mx4N), 8-phase double-buffered pipeline.
// grid: x = 20 N-tiles, y = nbgh*8 (bgh | mtile). bgh = bg*2 + uhalf.
#define LOAD_A(BUFO, MH) do { \
  _Pragma("unroll") \
  for (int i_ = 0; i_ < 4; ++i_) { \
    a[0][i_] = *(const short8*)(As + (BUFO) + am + (MH)*4096 + i_*1024 + sl0); \
    a[1][i_] = *(const short8*)(As + (BUFO) + am + (MH)*4096 + i_*1024 + sl1); \
  } } while (0)

#define LOAD_B(BUFO, NH, BR) do { \
  _Pragma("unroll") \
  for (int j_ = 0; j_ < 2; ++j_) { \
    BR[0][j_] = *(const short8*)(Bs + (BUFO) + bm + (NH)*2048 + j_*1024 + sl0); \
    BR[1][j_] = *(const short8*)(Bs + (BUFO) + bm + (NH)*2048 + j_*1024 + sl1); \
  } } while (0)

#define MFMA_Q(MH, NH, BR) do { \
  __builtin_amdgcn_s_setprio(1); \
  _Pragma("unroll") \
  for (int kk_ = 0; kk_ < 2; ++kk_) \
    _Pragma("unroll") \
    for (int i_ = 0; i_ < 4; ++i_) \
      _Pragma("unroll") \
      for (int j_ = 0; j_ < 2; ++j_) \
        acc[(MH)*4+i_][(NH)*2+j_] = __builtin_amdgcn_mfma_f32_16x16x32_bf16( \
            a[kk_][i_], BR[kk_][j_], acc[(MH)*4+i_][(NH)*2+j_], 0, 0, 0); \
  __builtin_amdgcn_s_setprio(0); } while (0)

__global__ __launch_bounds__(512, 2) void k_gemm_p(
    const u16* __restrict__ chb, const u16* __restrict__ Ubf,
    const float* __restrict__ bias, _Float16* __restrict__ P, int bgh_base)
{
  __shared__ u16 As[2 * 256 * 64];   // 64 KB: two K-tile buffers (halves stacked)
  __shared__ u16 Bs[2 * 256 * 64];   // 64 KB

  const int tid = threadIdx.x;
  const int wid = tid >> 6, lane = tid & 63;
  const int lane15 = lane & 15, quad = lane >> 4;
  const int wr = wid >> 2, wc = wid & 3;

  // XCD-aware bijective swizzle (nwg % 8 == 0 in both launch shapes)
  const int nwg = gridDim.x * gridDim.y;
  const int flat = blockIdx.y * gridDim.x + blockIdx.x;
  const int swz = (flat & 7) * (nwg >> 3) + (flat >> 3);
  const int bx = swz % 20;                 // N tile (0..19)
  const int by = swz / 20;
  const int bghl = by >> 3;                // local bgh slab in P
  const int bgh = bgh_base + bghl;
  const int bg = bgh >> 1, uhalf = bgh & 1;
  const int mtile = by & 7;

  // staging: half-tile = 128 rows x 64 cols bf16 = 16KB = 2 rounds x 512 thr x 16B
  // chunk idx = rnd*512+tid: row r=idx>>3 (0..127), slot s=idx&7, src chunk c=s^(r&7)
  const u16* aSrc[2]; const u16* bSrc[2]; int dOff[2];
#pragma unroll
  for (int rnd = 0; rnd < 2; ++rnd) {
    int idx = rnd * 512 + tid;
    int r = idx >> 3, s = idx & 7, c = s ^ (r & 7);
    aSrc[rnd] = chb + (size_t)(bg * 2048 + mtile * 256 + r) * 1024 + c * 8;
    bSrc[rnd] = Ubf + (size_t)(bx * 256 + r) * 2048 + uhalf * 1024 + c * 8;
    dOff[rnd] = idx * 8;                   // u16 units
  }
  auto STAGE_A = [&](int buf, int h, int T) {
#pragma unroll
    for (int rnd = 0; rnd < 2; ++rnd)
      async16(aSrc[rnd] + (size_t)h * 131072 + T * 64,
              As + buf * 16384 + h * 8192 + dOff[rnd]);
  };
  auto STAGE_B = [&](int buf, int h, int T) {
#pragma unroll
    for (int rnd = 0; rnd < 2; ++rnd)
      async16(bSrc[rnd] + (size_t)h * 262144 + T * 64,
              Bs + buf * 16384 + h * 8192 + dOff[rnd]);
  };

  // fragment read bases; m&7 == g&7 == lane15&7 (all tile offsets are mult of 8)
  const int sl0 = ((0 * 4 + quad) ^ (lane15 & 7)) * 8;   // kk=0 slot
  const int sl1 = ((1 * 4 + quad) ^ (lane15 & 7)) * 8;   // kk=1 slot
  const int am = (wr * 128 + lane15) * 64;   // + mh*4096 + i*1024
  const int bm = (wc * 64 + lane15) * 64;    // + nh*2048 + j*1024

  f32x4 acc[8][4];
#pragma unroll
  for (int m_ = 0; m_ < 8; ++m_)
#pragma unroll
    for (int n_ = 0; n_ < 4; ++n_) acc[m_][n_] = (f32x4){0.f, 0.f, 0.f, 0.f};

  short8 a[2][4], b0[2][2], b1[2][2];

  // prologue: tile0 fully + tile1 B-halves; tile1 A staged in iter0 p1/p2
  STAGE_B(0, 0, 0); STAGE_B(0, 1, 0); STAGE_A(0, 0, 0); STAGE_A(0, 1, 0);
  STAGE_B(1, 0, 1); STAGE_B(1, 1, 1);
  VMCNT4;                                  // tile0 landed (tile1-B in flight)
  BAR();

  for (int it = 0; it < 8; ++it) {
    const int T1 = 2 * it + 1, T2 = 2 * it + 2, T3 = 2 * it + 3;
    const bool e2 = (T2 < 16), e3 = (T3 < 16);
    // ---- phases 1-4: tile 2it from buf0 ----
    LOAD_A(0, 0); LOAD_B(0, 0, b0);
    STAGE_A(1, 0, T1);
    BAR(); MFMA_Q(0, 0, b0); BAR();

    LOAD_B(0, 1, b1);
    STAGE_A(1, 1, T1);
    BAR(); MFMA_Q(0, 1, b1); BAR();

    LOAD_A(0, 1);
    if (e2) STAGE_B(0, 0, T2);             // buf0 B free after phase 2
    BAR(); MFMA_Q(1, 0, b0); BAR();

    if (e2) STAGE_B(0, 1, T2);
    BAR(); MFMA_Q(1, 1, b1);
    if (e2) { VMCNT4; } else { VMCNT0; }   // tile 2it+1 fully landed
    BAR();
    // ---- phases 5-8: tile 2it+1 from buf1 ----
    LOAD_A(16384, 0); LOAD_B(16384, 0, b0);
    if (e2) STAGE_A(0, 0, T2);             // buf0 A free after phase 3
    BAR(); MFMA_Q(0, 0, b0); BAR();

    LOAD_B(16384, 1, b1);
    if (e2) STAGE_A(0, 1, T2);
    BAR(); MFMA_Q(0, 1, b1); BAR();

    LOAD_A(16384, 1);
    if (e3) STAGE_B(1, 0, T3);             // buf1 B free after phase 6
    BAR(); MFMA_Q(1, 0, b0); BAR();

    if (e3) STAGE_B(1, 1, T3);
    BAR(); MFMA_Q(1, 1, b1);
    if (e3) { VMCNT4; }                    // tile 2it+2 fully landed
    BAR();
  }

  // epilogue: bias (half0 only, pre-scaled) + fp16 store
  float bb[4];
#pragma unroll
  for (int nt = 0; nt < 4; ++nt) {
    int g = bx * 256 + wc * 64 + nt * 16 + lane15;
    float sc = (g < 4096) ? -L2E : (2.0f * L2E);
    bb[nt] = (uhalf == 0) ? bias[g] * sc : 0.f;
  }
  _Float16* Pb = P + ((size_t)bghl * 2048 + mtile * 256 + wr * 128) * 5120
               + bx * 256 + wc * 64;
#pragma unroll
  for (int mt = 0; mt < 8; ++mt)
#pragma unroll
    for (int rg = 0; rg < 4; ++rg) {
      _Float16* pr = Pb + (size_t)(mt * 16 + quad * 4 + rg) * 5120;
#pragma unroll
      for (int nt = 0; nt < 4; ++nt)
        pr[nt * 16 + lane15] = (_Float16)(acc[mt][nt][rg] + bb[nt]);
    }
}

// ---- fused: gather-add preact + gates + energy + softmax + combine ----
// Pl = base of this bg's half0 P-slab; half1 slab follows at +2048*5120.
__global__ __launch_bounds__(512, 4) void k_fused(
    const u16* __restrict__ chc, const _Float16* __restrict__ Pl,
    const int* __restrict__ ops, const float* __restrict__ eu,
    float* __restrict__ out, int bg)
{
  __shared__ u16 cS[32 * 1024];   // 64 KB; reused as float[8*1024] for h-reduce
  __shared__ float eS[32];

  const int tid = threadIdx.x;
  const int wave = tid >> 6, lane = tid & 63;
  const int flat = blockIdx.x;
  const int b_local = flat & 7;     // XCD-affine: same-XCD blocks share b
  const int step = flat >> 3;
  const int b = bg * 8 + b_local;

  float ureg[16];
  *(float4*)&ureg[0]  = *(const float4*)(eu + lane * 16);
  *(float4*)&ureg[4]  = *(const float4*)(eu + lane * 16 + 4);
  *(float4*)&ureg[8]  = *(const float4*)(eu + lane * 16 + 8);
  *(float4*)&ureg[12] = *(const float4*)(eu + lane * 16 + 12);
  float part = 0.f;
#pragma unroll
  for (int j = 0; j < 16; ++j) part += ureg[j] * ureg[j];
#pragma unroll
  for (int m = 1; m < 64; m <<= 1) part += __shfl_xor(part, m, 64);
  const float unorm = fmaxf(sqrtf(part), 1e-8f);

  u32 hPk[32];    // packed bf16 h: hPk[t*8 + sub*4 + (j>>1)] = cols (jj, jj+1)

  for (int t = 0; t < 4; ++t) {
    const int a = t * 8 + wave;
    const long opflat = (((long)step * 32 + b) * 32 + a) * 2;
    const int opL = ops[opflat], opR = ops[opflat + 1];
    const _Float16* PLp = Pl + (size_t)(b_local * 256 + opL) * 5120;
    const _Float16* PRp = Pl + ((size_t)2048 * 5120 + (size_t)(b_local * 256 + opR) * 5120);
    const u16* ccLr = chc + (size_t)(b * 256 + opL) * 1024;
    const u16* ccRr = chc + (size_t)(b * 256 + opR) * 1024;
    float dot = 0.f, nn = 0.f;
#pragma unroll
    for (int sub = 0; sub < 2; ++sub) {
      const int g8 = lane * 16 + sub * 8;
      h8 pre[5];
#pragma unroll
      for (int q = 0; q < 5; ++q)
        pre[q] = *(const h8*)(PLp + q * 1024 + g8) + *(const h8*)(PRp + q * 1024 + g8);
      const u16x8 cl = *(const u16x8*)(ccLr + g8);
      const u16x8 cr = *(const u16x8*)(ccRr + g8);
      u16x8 co;
      u32 lo = 0;
#pragma unroll
      for (int j = 0; j < 8; ++j) {
        const int jj = sub * 8 + j;
        float pi  = (float)pre[0][j];   // pre-scaled by -log2e
        float pfL = (float)pre[1][j];
        float pfR = (float)pre[2][j];
        float po  = (float)pre[3][j];
        float pu  = (float)pre[4][j];   // pre-scaled by +2*log2e
        float cv = sig2(pfL) * bf2f(cl[j]) + sig2(pfR) * bf2f(cr[j])
                 + sig2(pi) * tanh2(pu);
        float hv = sig2(po) * fast_tanh(cv);
        co[j] = f2bf(cv);
        if ((j & 1) == 0) lo = (u32)f2bf(hv);
        else hPk[t * 8 + sub * 4 + (j >> 1)] = lo | ((u32)f2bf(hv) << 16);
        dot += hv * ureg[jj];
        nn  += hv * hv;
      }
      *(u16x8*)(cS + a * 1024 + sub * 512 + lane * 8) = co;  // permuted, b128
    }
#pragma unroll
    for (int m = 1; m < 64; m <<= 1) {
      dot += __shfl_xor(dot, m, 64);
      nn  += __shfl_xor(nn, m, 64);
    }
    if (lane == 0) eS[a] = dot / (unorm * fmaxf(sqrtf(nn), 1e-8f));
  }
  __syncthreads();

  // softmax over 32 (from LDS broadcast reads)
  float w[32];
  float mx = -1e30f;
#pragma unroll
  for (int a = 0; a < 32; ++a) mx = fmaxf(mx, eS[a]);
  float S = 0.f;
#pragma unroll
  for (int a = 0; a < 32; ++a) { w[a] = __expf(eS[a] - mx); S += w[a]; }
  const float inv = 1.0f / S;

  // c combine: thread owns cols g0,g0+1; u32 column reads (2-way, free)
  const int g0 = tid * 2;
  const int p = ((g0 >> 3) & 1) * 512 + (g0 >> 4) * 8 + (g0 & 7);
  float sc0 = 0.f, sc1 = 0.f;
#pragma unroll
  for (int a = 0; a < 32; ++a) {
    const u32 cv = *(const u32*)(cS + a * 1024 + p);
    sc0 += w[a] * __uint_as_float(cv << 16);
    sc1 += w[a] * __uint_as_float(cv & 0xffff0000u);
  }
  float* orow = out + ((size_t)b * CHART_ROWS + 256 + step) * 2048;
  *(float2*)(orow + g0) = make_float2(sc0 * inv, sc1 * inv);
  __syncthreads();            // all cS reads done; buffer reused below

  // h partials: thread sums its 4 a-rows for its 16 cols, stash to LDS
  float* rS = (float*)cS;     // [wave][1024] floats, swizzled for b128 writes
  float ph[16];
#pragma unroll
  for (int jj = 0; jj < 16; ++jj) ph[jj] = 0.f;
#pragma unroll
  for (int t = 0; t < 4; ++t) {
    const float wa = w[t * 8 + wave];
#pragma unroll
    for (int k = 0; k < 8; ++k) {
      const u32 pk2 = hPk[t * 8 + k];
      const int jj0 = (k >> 2) * 8 + (k & 3) * 2;
      ph[jj0]     += wa * __uint_as_float(pk2 << 16);
      ph[jj0 + 1] += wa * __uint_as_float(pk2 & 0xffff0000u);
    }
  }
#pragma unroll
  for (int s = 0; s < 4; ++s) {
    float4 v = make_float4(ph[s * 4], ph[s * 4 + 1], ph[s * 4 + 2], ph[s * 4 + 3]);
    // col g = l*16 + s*4 + k stored at word wave*1024 + s*256 + l*4 + k
    *(float4*)(rS + wave * 1024 + s * 256 + lane * 4) = v;   // lane-contiguous
  }
  __syncthreads();

  // reduce 8 wave-partials for cols g0,g0+1
  const int l_own = g0 >> 4, s_ = (g0 >> 2) & 3, k_ = g0 & 3;
  float sh0 = 0.f, sh1 = 0.f;
#pragma unroll
  for (int w8 = 0; w8 < 8; ++w8) {
    const float2 v = *(const float2*)(rS + w8 * 1024 + s_ * 256 + l_own * 4 + k_);
    sh0 += v.x; sh1 += v.y;
  }
  *(float2*)(orow + 1024 + g0) = make_float2(sh0 * inv, sh1 * inv);
}

extern "C" void kernel_launch(void* const* d_in, const int* in_sizes, int n_in,
                              void* d_out, int out_size, void* d_ws, size_t ws_size,
                              hipStream_t stream) {
  (void)in_sizes; (void)n_in; (void)out_size;
  const float* chart = (const float*)d_in[0];
  const int*   ops   = (const int*)d_in[1];
  // d_in[2] = start_index (256, hard-coded)
  const float* U     = (const float*)d_in[3];
  const float* bias  = (const float*)d_in[4];
  const float* eu    = (const float*)d_in[5];
  float* out = (float*)d_out;
  char* ws = (char*)d_ws;

  u16*      Ubf = (u16*)ws;                       // 20,971,520 B
  u16*      chb = (u16*)(ws + 20971520);          // 16,777,216 B
  u16*      chc = (u16*)(ws + 37748736);          // 16,777,216 B
  _Float16* P   = (_Float16*)(ws + 54525952);     // big: 167,772,160 B (8 bgh slabs)
                                                  // small: 41,943,040 B (2 slabs)
  const size_t SLAB = (size_t)2048 * 5120;        // _Float16 per bgh slab
  const bool big = ws_size >= (size_t)54525952 + 8 * SLAB * 2;

  k_cvt_u<<<10240, 256, 0, stream>>>((const float4*)U, Ubf);
  k_cvt_chart<<<8192, 256, 0, stream>>>(chart, chb, chc, out);

  if (big) {
    k_gemm_p<<<dim3(20, 64), 512, 0, stream>>>(chb, Ubf, bias, P, 0);
    for (int bg = 0; bg < 4; ++bg)
      k_fused<<<1024, 512, 0, stream>>>(chc, P + (size_t)(2 * bg) * SLAB, ops, eu, out, bg);
  } else {
    for (int bg = 0; bg < 4; ++bg) {
      k_gemm_p<<<dim3(20, 16), 512, 0, stream>>>(chb, Ubf, bias, P, 2 * bg);
      k_fused<<<1024, 512, 0, stream>>>(chc, P, ops, eu, out, bg);
    }
  }
}